// Round 1
// baseline (36086.057 us; speedup 1.0000x reference)
//
#include <hip/hip_runtime.h>

#define U_ 1024
#define B_ 64
#define T_ 256
#define DIN_ 128
#define BT_ (B_*T_)

typedef __attribute__((ext_vector_type(4))) float f32x4;
typedef __attribute__((ext_vector_type(8))) short s16x8;
typedef __attribute__((ext_vector_type(4))) unsigned short u16x4;

__device__ inline unsigned short f2bf(float x){
  unsigned u = __float_as_uint(x);
  u += 0x7FFFu + ((u >> 16) & 1u);
  return (unsigned short)(u >> 16);
}
__device__ inline float bf2f(unsigned short b){ return __uint_as_float(((unsigned)b) << 16); }
__device__ inline float fast_rcp(float x){ return __builtin_amdgcn_rcpf(x); }
__device__ inline float fast_tanh(float x){
  float e = __expf(2.0f * x);
  return 1.0f - 2.0f * fast_rcp(e + 1.0f);
}
__device__ inline float fast_sig(float x){
  return fast_rcp(1.0f + __expf(-x));
}

// ---------------- init: zero state, prefill out with bo, zero barrier ----------------
__global__ void init_kernel(float* c, unsigned short* hb0, unsigned short* hb1,
                            float* out, const float* bo, unsigned* cnt){
  int i = blockIdx.x * 256 + threadIdx.x;   // grid 256x256 = 65536
  if (i < B_*U_){ c[i] = 0.f; hb0[i] = 0; hb1[i] = 0; }
  if (i < T_*B_) out[i] = bo[0];
  if (i == 0) *cnt = 0u;
}

// ---------------- transpose + bf16 convert: W[K][N] -> WT[N][K] ----------------
__global__ void transpose_bf_kernel(const float* W, unsigned short* WT, int K, int N){
  int ktiles = K >> 5;
  int kb = blockIdx.x % ktiles, nb = blockIdx.x / ktiles;
  __shared__ float tile[32][33];
  int x = threadIdx.x & 31, y8 = threadIdx.x >> 5;
  #pragma unroll
  for (int i = 0; i < 4; ++i){
    int y = y8*4 + i;
    tile[y][x] = W[(size_t)(kb*32 + y)*N + nb*32 + x];
  }
  __syncthreads();
  #pragma unroll
  for (int i = 0; i < 4; ++i){
    int y = y8*4 + i;
    WT[(size_t)(nb*32 + y)*K + kb*32 + x] = f2bf(tile[x][y]);
  }
}

// ---------------- embedding GEMM: C[M][1024] = act(A@B + bias), bf16 out ----------------
// tile 64m x 64n per block, 4 waves = m-quarters, 4 n-tiles of 16 per wave.
// BT is B^T bf16 [1024 n][K k]. act: 0=relu, 1=tanh.
template<int AF32>
__global__ __launch_bounds__(256) void gemm_embed(const void* Aptr, const unsigned short* BT,
                                                  const float* bias, unsigned short* Cout,
                                                  int K, int act){
  int nb = blockIdx.x & 15, mb = blockIdx.x >> 4;
  int lane = threadIdx.x & 63, w = threadIdx.x >> 6;
  int l15 = lane & 15, quad = lane >> 4;
  int m0 = mb*64 + w*16;
  int arow = m0 + l15;
  f32x4 acc[4];
  #pragma unroll
  for (int nt = 0; nt < 4; ++nt) acc[nt] = (f32x4){0.f,0.f,0.f,0.f};

  for (int k0 = 0; k0 < K; k0 += 32){
    int koff = k0 + quad*8;
    s16x8 a8;
    if (AF32){
      const float* ap = (const float*)Aptr + (size_t)arow*K + koff;
      f32x4 lo = *(const f32x4*)ap;
      f32x4 hi = *(const f32x4*)(ap + 4);
      a8[0]=(short)f2bf(lo[0]); a8[1]=(short)f2bf(lo[1]); a8[2]=(short)f2bf(lo[2]); a8[3]=(short)f2bf(lo[3]);
      a8[4]=(short)f2bf(hi[0]); a8[5]=(short)f2bf(hi[1]); a8[6]=(short)f2bf(hi[2]); a8[7]=(short)f2bf(hi[3]);
    } else {
      a8 = *(const s16x8*)((const unsigned short*)Aptr + (size_t)arow*K + koff);
    }
    #pragma unroll
    for (int nt = 0; nt < 4; ++nt){
      const unsigned short* bp = BT + (size_t)(nb*64 + nt*16 + l15)*K + koff;
      s16x8 b8 = *(const s16x8*)bp;
      acc[nt] = __builtin_amdgcn_mfma_f32_16x16x32_bf16(a8, b8, acc[nt], 0, 0, 0);
    }
  }
  #pragma unroll
  for (int nt = 0; nt < 4; ++nt){
    int col = nb*64 + nt*16 + l15;
    float bv = bias[col];
    #pragma unroll
    for (int r = 0; r < 4; ++r){
      int row = m0 + quad*4 + r;
      float v = acc[nt][r] + bv;
      v = (act == 0) ? fmaxf(v, 0.f) : fast_tanh(v);
      Cout[(size_t)row*U_ + col] = f2bf(v);
    }
  }
}

// ---------------- persistent sequential kernel ----------------
struct SeqP {
  const unsigned short *W1Tb, *WkTb, *WrTb, *tk, *xv;
  const float *b1, *bl, *V, *Wo;
  float *tq, *scores, *c, *out;
  unsigned short *ctxb, *hb0, *hb1;
  unsigned* cnt;
};

__device__ inline void gridbar(unsigned* cnt, unsigned barno){
  __syncthreads();
  if (threadIdx.x == 0){
    __threadfence();  // release (agent scope)
    __hip_atomic_fetch_add(cnt, 1u, __ATOMIC_RELAXED, __HIP_MEMORY_SCOPE_AGENT);
    unsigned tgt = barno << 8;  // barno * 256 blocks
    while (__hip_atomic_load(cnt, __ATOMIC_RELAXED, __HIP_MEMORY_SCOPE_AGENT) < tgt){
      __builtin_amdgcn_s_sleep(1);
    }
    __threadfence();  // acquire
  }
  __syncthreads();
}

__global__ __launch_bounds__(256, 1) void seq_kernel(SeqP p){
  const int bi = blockIdx.x;
  const int t  = threadIdx.x;
  const int lane = t & 63, w = t >> 6;
  const int l15 = lane & 15, quad = lane >> 4;
  __shared__ __align__(16) float smem[1536];
  unsigned barno = 0;

  for (int step = 0; step < T_; ++step){
    const unsigned short* hbR = (step & 1) ? p.hb1 : p.hb0;
    unsigned short*       hbW = (step & 1) ? p.hb0 : p.hb1;

    gridbar(p.cnt, ++barno);   // h_{t-1}, c visible

    // ---- Phase A: tq[b][j] = tanh(h@W1 + b1), MFMA on blocks 0..63 ----
    if (bi < 64){
      int jcol = bi*16 + l15;
      const unsigned short* ap = hbR + (size_t)(w*16 + l15)*U_;
      const unsigned short* bp = p.W1Tb + (size_t)jcol*U_;
      f32x4 acc = (f32x4){0.f,0.f,0.f,0.f};
      #pragma unroll 8
      for (int k = 0; k < U_; k += 32){
        s16x8 a8 = *(const s16x8*)(ap + k + quad*8);
        s16x8 b8 = *(const s16x8*)(bp + k + quad*8);
        acc = __builtin_amdgcn_mfma_f32_16x16x32_bf16(a8, b8, acc, 0, 0, 0);
      }
      float bj = p.b1[jcol];
      #pragma unroll
      for (int r = 0; r < 4; ++r){
        int b = w*16 + quad*4 + r;
        p.tq[b*U_ + jcol] = fast_tanh(acc[r] + bj);
      }
    }

    gridbar(p.cnt, ++barno);   // tq visible

    // ---- Phase B1: scores[b][t] = sum_u V[u]*(tq+tk)/(1+tq*tk) ----
    {
      int b = bi >> 2, tg = bi & 3;
      float tqv[16], Vv[16];
      const float* tqp = p.tq + b*U_ + lane*16;
      const float* Vp  = p.V + lane*16;
      #pragma unroll
      for (int i = 0; i < 16; i += 4){
        *(f32x4*)&tqv[i] = *(const f32x4*)(tqp + i);
        *(f32x4*)&Vv[i]  = *(const f32x4*)(Vp + i);
      }
      int tb = tg*64 + w*16;
      for (int tt = 0; tt < 16; ++tt){
        int trow = tb + tt;
        const unsigned short* kp = p.tk + (size_t)(b*T_ + trow)*U_ + lane*16;
        s16x8 k0 = *(const s16x8*)kp;
        s16x8 k1 = *(const s16x8*)(kp + 8);
        float s = 0.f;
        #pragma unroll
        for (int e = 0; e < 8; ++e){
          float kf = bf2f((unsigned short)k0[e]);
          float num = tqv[e] + kf;
          float den = fmaf(tqv[e], kf, 1.0f);
          s += Vv[e] * num * fast_rcp(den);
        }
        #pragma unroll
        for (int e = 0; e < 8; ++e){
          float kf = bf2f((unsigned short)k1[e]);
          float num = tqv[8+e] + kf;
          float den = fmaf(tqv[8+e], kf, 1.0f);
          s += Vv[8+e] * num * fast_rcp(den);
        }
        #pragma unroll
        for (int mk = 32; mk >= 1; mk >>= 1) s += __shfl_xor(s, mk, 64);
        if (lane == 0) p.scores[b*T_ + trow] = s;
      }
    }

    gridbar(p.cnt, ++barno);   // scores visible

    // ---- Phase B2: softmax over t (redundant per u-group), ctx accumulate ----
    {
      int b = bi >> 2, ug = bi & 3;
      float* ew  = smem;        // 256
      float* tmp = smem + 256;  // 8
      float* red = smem + 264;  // 4*64*4 = 1024
      float s = p.scores[b*T_ + t];
      float mx = s;
      #pragma unroll
      for (int mk = 32; mk >= 1; mk >>= 1) mx = fmaxf(mx, __shfl_xor(mx, mk, 64));
      if (lane == 0) tmp[w] = mx;
      __syncthreads();
      mx = fmaxf(fmaxf(tmp[0], tmp[1]), fmaxf(tmp[2], tmp[3]));
      float e = __expf(s - mx);
      float sum = e;
      #pragma unroll
      for (int mk = 32; mk >= 1; mk >>= 1) sum += __shfl_xor(sum, mk, 64);
      ew[t] = e;
      if (lane == 0) tmp[4 + w] = sum;
      __syncthreads();
      float rd = fast_rcp(tmp[4] + tmp[5] + tmp[6] + tmp[7]);

      int ui = t & 63, tg4 = t >> 6;
      int u = ug*256 + ui*4;
      const unsigned short* xp = p.xv + (size_t)b*T_*U_ + u;
      f32x4 a = (f32x4){0.f,0.f,0.f,0.f};
      for (int t8 = tg4; t8 < T_; t8 += 4){
        float wg = ew[t8];
        u16x4 x4 = *(const u16x4*)(xp + (size_t)t8*U_);
        a[0] = fmaf(wg, bf2f(x4[0]), a[0]);
        a[1] = fmaf(wg, bf2f(x4[1]), a[1]);
        a[2] = fmaf(wg, bf2f(x4[2]), a[2]);
        a[3] = fmaf(wg, bf2f(x4[3]), a[3]);
      }
      *(f32x4*)&red[(tg4*64 + ui)*4] = a;
      __syncthreads();
      if (tg4 == 0){
        f32x4 r0 = *(f32x4*)&red[(0*64 + ui)*4];
        f32x4 r1 = *(f32x4*)&red[(1*64 + ui)*4];
        f32x4 r2 = *(f32x4*)&red[(2*64 + ui)*4];
        f32x4 r3 = *(f32x4*)&red[(3*64 + ui)*4];
        u16x4 cv;
        cv[0] = f2bf((r0[0]+r1[0]+r2[0]+r3[0]) * rd);
        cv[1] = f2bf((r0[1]+r1[1]+r2[1]+r3[1]) * rd);
        cv[2] = f2bf((r0[2]+r1[2]+r2[2]+r3[2]) * rd);
        cv[3] = f2bf((r0[3]+r1[3]+r2[3]+r3[3]) * rd);
        *(u16x4*)(p.ctxb + b*U_ + u) = cv;
      }
    }

    gridbar(p.cnt, ++barno);   // ctxb visible

    // ---- Phase C: z = ctx@Wk + h@Wr (+bl), LSTM update, out partials ----
    {
      int ub = bi*4;
      int gate = l15 >> 2, uo = l15 & 3;
      size_t jcol = (size_t)gate*U_ + ub + uo;
      const unsigned short* akp = p.ctxb + (size_t)(w*16 + l15)*U_;
      const unsigned short* ahp = hbR   + (size_t)(w*16 + l15)*U_;
      const unsigned short* bkp = p.WkTb + jcol*U_;
      const unsigned short* brp = p.WrTb + jcol*U_;
      f32x4 acc = (f32x4){0.f,0.f,0.f,0.f};
      #pragma unroll 8
      for (int k = 0; k < U_; k += 32){
        s16x8 a8 = *(const s16x8*)(akp + k + quad*8);
        s16x8 b8 = *(const s16x8*)(bkp + k + quad*8);
        acc = __builtin_amdgcn_mfma_f32_16x16x32_bf16(a8, b8, acc, 0, 0, 0);
      }
      #pragma unroll 8
      for (int k = 0; k < U_; k += 32){
        s16x8 a8 = *(const s16x8*)(ahp + k + quad*8);
        s16x8 b8 = *(const s16x8*)(brp + k + quad*8);
        acc = __builtin_amdgcn_mfma_f32_16x16x32_bf16(a8, b8, acc, 0, 0, 0);
      }
      float* zs = smem;         // 16*68
      float* op = smem + 1088;  // 4*64
      #pragma unroll
      for (int r = 0; r < 4; ++r) zs[l15*68 + w*16 + quad*4 + r] = acc[r];
      __syncthreads();
      {
        int b = t & 63, ui = t >> 6;
        int u = ub + ui;
        float zi = zs[(0*4 + ui)*68 + b] + p.bl[0*U_ + u];
        float zf = zs[(1*4 + ui)*68 + b] + p.bl[1*U_ + u];
        float zg = zs[(2*4 + ui)*68 + b] + p.bl[2*U_ + u];
        float zo = zs[(3*4 + ui)*68 + b] + p.bl[3*U_ + u];
        float ig = fast_sig(zi), fg = fast_sig(zf);
        float gg = fast_tanh(zg), og = fast_sig(zo);
        float cold = p.c[u*64 + b];      // c layout [U][B] for coalescing
        float cn = fg*cold + ig*gg;
        float hn = og * fast_tanh(cn);
        p.c[u*64 + b] = cn;
        hbW[b*U_ + u] = f2bf(hn);
        op[ui*64 + b] = hn * p.Wo[u];
      }
      __syncthreads();
      if (t < 64){
        float po = op[t] + op[64 + t] + op[128 + t] + op[192 + t];
        atomicAdd(&p.out[step*64 + t], po);
      }
    }
  }
}

extern "C" void kernel_launch(void* const* d_in, const int* in_sizes, int n_in,
                              void* d_out, int out_size, void* d_ws, size_t ws_size,
                              hipStream_t stream){
  const float* inputs = (const float*)d_in[0];
  const float* We1 = (const float*)d_in[1];
  const float* be1 = (const float*)d_in[2];
  const float* We2 = (const float*)d_in[3];
  const float* be2 = (const float*)d_in[4];
  const float* W1  = (const float*)d_in[5];
  const float* b1  = (const float*)d_in[6];
  const float* W2  = (const float*)d_in[7];
  const float* b2  = (const float*)d_in[8];
  const float* V   = (const float*)d_in[9];
  // d_in[10] = bV: softmax shift-invariant, dropped
  const float* Wk  = (const float*)d_in[11];
  const float* Wr  = (const float*)d_in[12];
  const float* bl  = (const float*)d_in[13];
  const float* Wo  = (const float*)d_in[14];
  const float* bo  = (const float*)d_in[15];
  float* out = (float*)d_out;

  char* ws = (char*)d_ws;
  size_t off = 0;
  auto alloc = [&](size_t bytes) -> void* {
    void* pp = ws + off;
    off = (off + bytes + 255) & ~(size_t)255;
    return pp;
  };
  unsigned short* We1Tb = (unsigned short*)alloc((size_t)1024*128*2);
  unsigned short* We2Tb = (unsigned short*)alloc((size_t)1024*1024*2);
  unsigned short* W2Tb  = (unsigned short*)alloc((size_t)1024*1024*2);
  unsigned short* W1Tb  = (unsigned short*)alloc((size_t)1024*1024*2);
  unsigned short* WkTb  = (unsigned short*)alloc((size_t)4096*1024*2);
  unsigned short* WrTb  = (unsigned short*)alloc((size_t)4096*1024*2);
  unsigned short* h1b   = (unsigned short*)alloc((size_t)BT_*U_*2);
  unsigned short* xv    = (unsigned short*)alloc((size_t)BT_*U_*2);
  unsigned short* tk    = (unsigned short*)alloc((size_t)BT_*U_*2);
  float*          c     = (float*)alloc((size_t)B_*U_*4);
  unsigned short* hb0   = (unsigned short*)alloc((size_t)B_*U_*2);
  unsigned short* hb1   = (unsigned short*)alloc((size_t)B_*U_*2);
  unsigned short* ctxb  = (unsigned short*)alloc((size_t)B_*U_*2);
  float*          tq    = (float*)alloc((size_t)B_*U_*4);
  float*          scores= (float*)alloc((size_t)B_*T_*4);
  unsigned*       cnt   = (unsigned*)alloc(256);
  if (ws_size < off) return;  // workspace too small: fail loudly (validation mismatch)

  init_kernel<<<256, 256, 0, stream>>>(c, hb0, hb1, out, bo, cnt);
  transpose_bf_kernel<<<(128/32)*(1024/32),  256, 0, stream>>>(We1, We1Tb, 128, 1024);
  transpose_bf_kernel<<<(1024/32)*(1024/32), 256, 0, stream>>>(We2, We2Tb, 1024, 1024);
  transpose_bf_kernel<<<(1024/32)*(1024/32), 256, 0, stream>>>(W2,  W2Tb,  1024, 1024);
  transpose_bf_kernel<<<(1024/32)*(1024/32), 256, 0, stream>>>(W1,  W1Tb,  1024, 1024);
  transpose_bf_kernel<<<(1024/32)*(4096/32), 256, 0, stream>>>(Wk,  WkTb,  1024, 4096);
  transpose_bf_kernel<<<(1024/32)*(4096/32), 256, 0, stream>>>(Wr,  WrTb,  1024, 4096);

  gemm_embed<1><<<4096, 256, 0, stream>>>((const void*)inputs, We1Tb, be1, h1b, DIN_, 0);
  gemm_embed<0><<<4096, 256, 0, stream>>>((const void*)h1b,    We2Tb, be2, xv,  U_,   0);
  gemm_embed<0><<<4096, 256, 0, stream>>>((const void*)xv,     W2Tb,  b2,  tk,  U_,   1);

  SeqP sp;
  sp.W1Tb = W1Tb; sp.WkTb = WkTb; sp.WrTb = WrTb; sp.tk = tk; sp.xv = xv;
  sp.b1 = b1; sp.bl = bl; sp.V = V; sp.Wo = Wo;
  sp.tq = tq; sp.scores = scores; sp.c = c; sp.out = out;
  sp.ctxb = ctxb; sp.hb0 = hb0; sp.hb1 = hb1; sp.cnt = cnt;
  void* args[] = { &sp };
  hipLaunchCooperativeKernel((void*)seq_kernel, dim3(256), dim3(256), args, 0, stream);
}

// Round 5
// 32497.906 us; speedup vs baseline: 1.1104x; 1.1104x over previous
//
#include <hip/hip_runtime.h>

#define U_ 1024
#define B_ 64
#define T_ 256
#define DIN_ 128
#define BT_ (B_*T_)
#define G_ 512   // seq kernel grid: 2 blocks/CU co-residency guaranteed by launch_bounds(256,2)

typedef __attribute__((ext_vector_type(4))) float f32x4;
typedef __attribute__((ext_vector_type(8))) short s16x8;
typedef __attribute__((ext_vector_type(4))) unsigned short u16x4;

__device__ inline unsigned short f2bf(float x){
  unsigned u = __float_as_uint(x);
  u += 0x7FFFu + ((u >> 16) & 1u);
  return (unsigned short)(u >> 16);
}
__device__ inline float bf2f(unsigned short b){ return __uint_as_float(((unsigned)b) << 16); }
__device__ inline float fast_rcp(float x){ return __builtin_amdgcn_rcpf(x); }
__device__ inline float fast_tanh(float x){
  float e = __expf(2.0f * x);
  return 1.0f - 2.0f * fast_rcp(e + 1.0f);
}
__device__ inline float fast_sig(float x){
  return fast_rcp(1.0f + __expf(-x));
}

// ---------------- init ----------------
__global__ void init_kernel(float* c, unsigned short* hb0, unsigned short* hb1,
                            unsigned* cnt, unsigned* rel){
  int i = blockIdx.x * 256 + threadIdx.x;   // grid 256x256 = 65536
  if (i < B_*U_){ c[i] = 0.f; hb0[i] = 0; hb1[i] = 0; }
  if (i < 64*32){ cnt[i] = 0u; rel[i] = 0u; }
}

// ---------------- transpose + bf16 convert: W[K][N] -> WT[N][K] ----------------
__global__ void transpose_bf_kernel(const float* W, unsigned short* WT, int K, int N){
  int ktiles = K >> 5;
  int kb = blockIdx.x % ktiles, nb = blockIdx.x / ktiles;
  __shared__ float tile[32][33];
  int x = threadIdx.x & 31, y8 = threadIdx.x >> 5;
  #pragma unroll
  for (int i = 0; i < 4; ++i){
    int y = y8*4 + i;
    tile[y][x] = W[(size_t)(kb*32 + y)*N + nb*32 + x];
  }
  __syncthreads();
  #pragma unroll
  for (int i = 0; i < 4; ++i){
    int y = y8*4 + i;
    WT[(size_t)(nb*32 + y)*K + kb*32 + x] = f2bf(tile[x][y]);
  }
}

// ---------------- embedding GEMMs (once per launch) ----------------
template<int AF32>
__global__ __launch_bounds__(256) void gemm_embed(const void* Aptr, const unsigned short* BT,
                                                  const float* bias, unsigned short* Cout,
                                                  int K, int act){
  int nb = blockIdx.x & 15, mb = blockIdx.x >> 4;
  int lane = threadIdx.x & 63, w = threadIdx.x >> 6;
  int l15 = lane & 15, quad = lane >> 4;
  int m0 = mb*64 + w*16;
  int arow = m0 + l15;
  f32x4 acc[4];
  #pragma unroll
  for (int nt = 0; nt < 4; ++nt) acc[nt] = (f32x4){0.f,0.f,0.f,0.f};

  for (int k0 = 0; k0 < K; k0 += 32){
    int koff = k0 + quad*8;
    s16x8 a8;
    if (AF32){
      const float* ap = (const float*)Aptr + (size_t)arow*K + koff;
      f32x4 lo = *(const f32x4*)ap;
      f32x4 hi = *(const f32x4*)(ap + 4);
      a8[0]=(short)f2bf(lo[0]); a8[1]=(short)f2bf(lo[1]); a8[2]=(short)f2bf(lo[2]); a8[3]=(short)f2bf(lo[3]);
      a8[4]=(short)f2bf(hi[0]); a8[5]=(short)f2bf(hi[1]); a8[6]=(short)f2bf(hi[2]); a8[7]=(short)f2bf(hi[3]);
    } else {
      a8 = *(const s16x8*)((const unsigned short*)Aptr + (size_t)arow*K + koff);
    }
    #pragma unroll
    for (int nt = 0; nt < 4; ++nt){
      const unsigned short* bp = BT + (size_t)(nb*64 + nt*16 + l15)*K + koff;
      s16x8 b8 = *(const s16x8*)bp;
      acc[nt] = __builtin_amdgcn_mfma_f32_16x16x32_bf16(a8, b8, acc[nt], 0, 0, 0);
    }
  }
  #pragma unroll
  for (int nt = 0; nt < 4; ++nt){
    int col = nb*64 + nt*16 + l15;
    float bv = bias[col];
    #pragma unroll
    for (int r = 0; r < 4; ++r){
      int row = m0 + quad*4 + r;
      float v = acc[nt][r] + bv;
      v = (act == 0) ? fmaxf(v, 0.f) : fast_tanh(v);
      Cout[(size_t)row*U_ + col] = f2bf(v);
    }
  }
}

// ---------------- persistent sequential kernel ----------------
struct SeqP {
  const unsigned short *W1Tb, *WkTb, *WrTb, *tk, *xv;
  const float *b1, *bl, *V, *Wo, *bo;
  float *tq, *scores, *c, *zh, *out_part, *out;
  unsigned short *ctxb, *hb0, *hb1;
  unsigned *cnt, *rel;
};

// Distributed grid barrier: 64 arrive lines (8 RMWs each), block-0 wave gathers,
// 64 release lines polled read-only with sleep backoff. Device-scope fences;
// no dispatch-order assumption (all blocks arrive before any releases).
__device__ inline void gridbar(unsigned* cnt, unsigned* rel, unsigned barno){
  __syncthreads();
  if (threadIdx.x == 0){
    __threadfence();
    __hip_atomic_fetch_add(&cnt[(blockIdx.x & 63) * 32], 1u, __ATOMIC_RELAXED, __HIP_MEMORY_SCOPE_AGENT);
  }
  if (blockIdx.x == 0){
    if (threadIdx.x < 64){
      const unsigned tgt = barno * G_;
      for (;;){
        unsigned v = __hip_atomic_load(&cnt[threadIdx.x * 32], __ATOMIC_RELAXED, __HIP_MEMORY_SCOPE_AGENT);
        #pragma unroll
        for (int mk = 32; mk >= 1; mk >>= 1) v += __shfl_xor(v, mk, 64);
        if (v >= tgt) break;
        __builtin_amdgcn_s_sleep(2);
      }
      __hip_atomic_store(&rel[threadIdx.x * 32], barno, __ATOMIC_RELAXED, __HIP_MEMORY_SCOPE_AGENT);
    }
    if (threadIdx.x == 0) __threadfence();
  } else {
    if (threadIdx.x == 0){
      unsigned* myrel = &rel[(blockIdx.x & 63) * 32];
      while (__hip_atomic_load(myrel, __ATOMIC_RELAXED, __HIP_MEMORY_SCOPE_AGENT) < barno)
        __builtin_amdgcn_s_sleep(8);
      __threadfence();
    }
  }
  __syncthreads();
}

__device__ inline void out_reduce(const SeqP& p, int b, int sidx, float* smem,
                                  int t, int lane, int w){
  float v = p.out_part[b*256 + t];
  #pragma unroll
  for (int mk = 32; mk >= 1; mk >>= 1) v += __shfl_xor(v, mk, 64);
  if (lane == 0) smem[w] = v;
  __syncthreads();
  if (t == 0) p.out[sidx*64 + b] = smem[0] + smem[1] + smem[2] + smem[3] + p.bo[0];
  __syncthreads();
}

__global__ __launch_bounds__(256, 2) void seq_kernel(SeqP p){
  const int bi = blockIdx.x;
  const int t  = threadIdx.x;
  const int lane = t & 63, w = t >> 6;
  const int l15 = lane & 15, quad = lane >> 4;
  __shared__ __align__(16) float smem[1664];
  unsigned barno = 0;

  for (int step = 0; step < T_; ++step){
    const unsigned short* hbR = (step & 1) ? p.hb1 : p.hb0;
    unsigned short*       hbW = (step & 1) ? p.hb0 : p.hb1;

    gridbar(p.cnt, p.rel, ++barno);   // h_{t-1}, c, out_part visible

    // ---- Phase A: tq (blocks 0..63), zh = h@Wr + bl (blocks 64..191),
    //               out reduction for step-1 (blocks 448..511) ----
    if (bi < 64){
      int jcol = bi*16 + l15;
      const unsigned short* ap = hbR + (size_t)(w*16 + l15)*U_;
      const unsigned short* bp = p.W1Tb + (size_t)jcol*U_;
      f32x4 acc = (f32x4){0.f,0.f,0.f,0.f};
      #pragma unroll 8
      for (int k = 0; k < U_; k += 32){
        s16x8 a8 = *(const s16x8*)(ap + k + quad*8);
        s16x8 b8 = *(const s16x8*)(bp + k + quad*8);
        acc = __builtin_amdgcn_mfma_f32_16x16x32_bf16(a8, b8, acc, 0, 0, 0);
      }
      float bj = p.b1[jcol];
      float* tqs = smem;   // 16*68
      #pragma unroll
      for (int r = 0; r < 4; ++r)
        tqs[l15*68 + w*16 + quad*4 + r] = fast_tanh(acc[r] + bj);
      __syncthreads();
      if (t < 64){
        float* dst = p.tq + (size_t)t*U_ + bi*16;
        #pragma unroll
        for (int cc = 0; cc < 16; cc += 4){
          f32x4 o = (f32x4){tqs[(cc+0)*68 + t], tqs[(cc+1)*68 + t],
                            tqs[(cc+2)*68 + t], tqs[(cc+3)*68 + t]};
          *(f32x4*)(dst + cc) = o;
        }
      }
    } else if (bi < 192){
      int bz = bi - 64;    // 32 cols each
      const unsigned short* ap = hbR + (size_t)(w*16 + l15)*U_;
      int jc0 = bz*32 + l15, jc1 = jc0 + 16;
      const unsigned short* bp0 = p.WrTb + (size_t)jc0*U_;
      const unsigned short* bp1 = p.WrTb + (size_t)jc1*U_;
      f32x4 acc0 = (f32x4){0.f,0.f,0.f,0.f}, acc1 = acc0;
      #pragma unroll 8
      for (int k = 0; k < U_; k += 32){
        s16x8 a8 = *(const s16x8*)(ap + k + quad*8);
        acc0 = __builtin_amdgcn_mfma_f32_16x16x32_bf16(a8, *(const s16x8*)(bp0 + k + quad*8), acc0, 0, 0, 0);
        acc1 = __builtin_amdgcn_mfma_f32_16x16x32_bf16(a8, *(const s16x8*)(bp1 + k + quad*8), acc1, 0, 0, 0);
      }
      float bl0 = p.bl[jc0], bl1 = p.bl[jc1];
      int brow = w*16 + quad*4;
      f32x4 s0, s1;
      #pragma unroll
      for (int r = 0; r < 4; ++r){ s0[r] = acc0[r] + bl0; s1[r] = acc1[r] + bl1; }
      *(f32x4*)(p.zh + (size_t)jc0*64 + brow) = s0;
      *(f32x4*)(p.zh + (size_t)jc1*64 + brow) = s1;
    } else if (bi >= 448){
      if (step > 0) out_reduce(p, bi - 448, step - 1, smem, t, lane, w);
    }

    gridbar(p.cnt, p.rel, ++barno);   // tq, zh visible

    // ---- Phase B1: scores[b][t], all 512 blocks: b = bi>>3, 32 t-rows each ----
    {
      int b = bi >> 3, tg = bi & 7;
      float tqv[16], Vv[16];
      const float* tqp = p.tq + b*U_ + lane*16;
      const float* Vp  = p.V + lane*16;
      #pragma unroll
      for (int i = 0; i < 16; i += 4){
        *(f32x4*)&tqv[i] = *(const f32x4*)(tqp + i);
        *(f32x4*)&Vv[i]  = *(const f32x4*)(Vp + i);
      }
      int trow = tg*32 + w*8;
      const unsigned short* kp = p.tk + (size_t)(b*T_ + trow)*U_ + lane*16;
      float sr[8];
      #pragma unroll
      for (int rr = 0; rr < 8; ++rr){
        s16x8 k0 = *(const s16x8*)(kp + (size_t)rr*U_);
        s16x8 k1 = *(const s16x8*)(kp + (size_t)rr*U_ + 8);
        float s = 0.f;
        #pragma unroll
        for (int e = 0; e < 8; ++e){
          float kf = bf2f((unsigned short)k0[e]);
          float num = tqv[e] + kf;
          float den = fmaf(tqv[e], kf, 1.0f);
          s += Vv[e] * num * fast_rcp(den);
        }
        #pragma unroll
        for (int e = 0; e < 8; ++e){
          float kf = bf2f((unsigned short)k1[e]);
          float num = tqv[8+e] + kf;
          float den = fmaf(tqv[8+e], kf, 1.0f);
          s += Vv[8+e] * num * fast_rcp(den);
        }
        sr[rr] = s;
      }
      #pragma unroll
      for (int mk = 32; mk >= 1; mk >>= 1){
        #pragma unroll
        for (int rr = 0; rr < 8; ++rr) sr[rr] += __shfl_xor(sr[rr], mk, 64);
      }
      if (lane == 0){
        *(f32x4*)(p.scores + b*T_ + trow)     = (f32x4){sr[0], sr[1], sr[2], sr[3]};
        *(f32x4*)(p.scores + b*T_ + trow + 4) = (f32x4){sr[4], sr[5], sr[6], sr[7]};
      }
    }

    gridbar(p.cnt, p.rel, ++barno);   // scores visible

    // ---- Phase B2: softmax (redundant per block) + ctx chunk, b = bi>>3, 128 u's ----
    {
      int b = bi >> 3, ug = bi & 7;
      float* ew  = smem;        // 256
      float* tmp = smem + 256;  // 16
      float* red = smem + 272;  // 8*32*4 = 1024
      float s = p.scores[b*T_ + t];
      float mx = s;
      #pragma unroll
      for (int mk = 32; mk >= 1; mk >>= 1) mx = fmaxf(mx, __shfl_xor(mx, mk, 64));
      if (lane == 0) tmp[w] = mx;
      __syncthreads();
      mx = fmaxf(fmaxf(tmp[0], tmp[1]), fmaxf(tmp[2], tmp[3]));
      float e = __expf(s - mx);
      ew[t] = e;
      float sum = e;
      #pragma unroll
      for (int mk = 32; mk >= 1; mk >>= 1) sum += __shfl_xor(sum, mk, 64);
      if (lane == 0) tmp[4 + w] = sum;
      __syncthreads();
      float rd = fast_rcp(tmp[4] + tmp[5] + tmp[6] + tmp[7]);

      int ui = t & 31, tgp = t >> 5;
      int u = ug*128 + ui*4;
      const unsigned short* xp = p.xv + (size_t)b*T_*U_ + u;
      f32x4 a = (f32x4){0.f,0.f,0.f,0.f};
      for (int t8 = tgp; t8 < T_; t8 += 8){
        float wg = ew[t8];
        u16x4 x4 = *(const u16x4*)(xp + (size_t)t8*U_);
        a[0] = fmaf(wg, bf2f(x4[0]), a[0]);
        a[1] = fmaf(wg, bf2f(x4[1]), a[1]);
        a[2] = fmaf(wg, bf2f(x4[2]), a[2]);
        a[3] = fmaf(wg, bf2f(x4[3]), a[3]);
      }
      *(f32x4*)&red[(tgp*32 + ui)*4] = a;
      __syncthreads();
      if (t < 32){
        f32x4 r = (f32x4){0.f,0.f,0.f,0.f};
        #pragma unroll
        for (int g = 0; g < 8; ++g){
          f32x4 rr = *(f32x4*)&red[(g*32 + t)*4];
          r[0]+=rr[0]; r[1]+=rr[1]; r[2]+=rr[2]; r[3]+=rr[3];
        }
        u16x4 cv;
        cv[0]=f2bf(r[0]*rd); cv[1]=f2bf(r[1]*rd); cv[2]=f2bf(r[2]*rd); cv[3]=f2bf(r[3]*rd);
        *(u16x4*)(p.ctxb + (size_t)b*U_ + ug*128 + t*4) = cv;
      }
    }

    gridbar(p.cnt, p.rel, ++barno);   // ctxb visible

    // ---- Phase C: z = ctx@Wk + zh, LSTM update (blocks 0..255, 4 u's each) ----
    if (bi < 256){
      int ub = bi*4;
      int gate = l15 >> 2, uo = l15 & 3;
      size_t jcol = (size_t)gate*U_ + ub + uo;
      const unsigned short* akp = p.ctxb + (size_t)(w*16 + l15)*U_;
      const unsigned short* bp0 = p.WkTb + jcol*U_;
      f32x4 acc = (f32x4){0.f,0.f,0.f,0.f};
      #pragma unroll 8
      for (int k = 0; k < U_; k += 32){
        s16x8 a8 = *(const s16x8*)(akp + k + quad*8);
        acc = __builtin_amdgcn_mfma_f32_16x16x32_bf16(a8, *(const s16x8*)(bp0 + k + quad*8), acc, 0, 0, 0);
      }
      int brow = w*16 + quad*4;
      f32x4 z0 = *(f32x4*)(p.zh + jcol*64 + brow);
      #pragma unroll
      for (int r = 0; r < 4; ++r) acc[r] += z0[r];
      float* zs = smem;          // 16*68 = 1088
      float* hs = smem + 1088;   // 256
      float* op = smem + 1344;   // 256
      *(f32x4*)&zs[l15*68 + brow] = acc;
      __syncthreads();
      {
        int b = t & 63, ui = t >> 6;   // ui in 0..3
        int u = ub + ui;
        float zi = zs[(0*4 + ui)*68 + b];
        float zf = zs[(1*4 + ui)*68 + b];
        float zg = zs[(2*4 + ui)*68 + b];
        float zo = zs[(3*4 + ui)*68 + b];
        float ig = fast_sig(zi), fg = fast_sig(zf);
        float gg = fast_tanh(zg), og = fast_sig(zo);
        float cold = p.c[u*64 + b];
        float cn = fg*cold + ig*gg;
        float hn = og * fast_tanh(cn);
        p.c[u*64 + b] = cn;
        hs[ui*64 + b] = hn;
        op[ui*64 + b] = hn * p.Wo[u];
      }
      __syncthreads();
      if (t < 64){
        u16x4 h0;
        #pragma unroll
        for (int k = 0; k < 4; ++k) h0[k] = f2bf(hs[k*64 + t]);
        *(u16x4*)(hbW + (size_t)t*U_ + ub) = h0;
        float po = op[t] + op[64 + t] + op[128 + t] + op[192 + t];
        p.out_part[t*256 + bi] = po;
      }
    }
  }

  gridbar(p.cnt, p.rel, ++barno);   // final out_part visible
  if (bi >= 448) out_reduce(p, bi - 448, T_ - 1, smem, t, lane, w);
}

extern "C" void kernel_launch(void* const* d_in, const int* in_sizes, int n_in,
                              void* d_out, int out_size, void* d_ws, size_t ws_size,
                              hipStream_t stream){
  const float* inputs = (const float*)d_in[0];
  const float* We1 = (const float*)d_in[1];
  const float* be1 = (const float*)d_in[2];
  const float* We2 = (const float*)d_in[3];
  const float* be2 = (const float*)d_in[4];
  const float* W1  = (const float*)d_in[5];
  const float* b1  = (const float*)d_in[6];
  const float* W2  = (const float*)d_in[7];
  const float* b2  = (const float*)d_in[8];
  const float* V   = (const float*)d_in[9];
  // d_in[10] = bV: softmax shift-invariant, dropped
  const float* Wk  = (const float*)d_in[11];
  const float* Wr  = (const float*)d_in[12];
  const float* bl  = (const float*)d_in[13];
  const float* Wo  = (const float*)d_in[14];
  const float* bo  = (const float*)d_in[15];
  float* out = (float*)d_out;

  char* ws = (char*)d_ws;
  size_t off = 0;
  auto alloc = [&](size_t bytes) -> void* {
    void* pp = ws + off;
    off = (off + bytes + 255) & ~(size_t)255;
    return pp;
  };
  // h1 (GEMM-1 output) is dead after GEMM-2; tk (GEMM-3 output) aliases it.
  unsigned short* We1Tb = (unsigned short*)alloc((size_t)1024*128*2);
  unsigned short* We2Tb = (unsigned short*)alloc((size_t)1024*1024*2);
  unsigned short* W2Tb  = (unsigned short*)alloc((size_t)1024*1024*2);
  unsigned short* W1Tb  = (unsigned short*)alloc((size_t)1024*1024*2);
  unsigned short* WkTb  = (unsigned short*)alloc((size_t)4096*1024*2);
  unsigned short* WrTb  = (unsigned short*)alloc((size_t)4096*1024*2);
  unsigned short* h1tk  = (unsigned short*)alloc((size_t)BT_*U_*2);  // h1, then tk
  unsigned short* xv    = (unsigned short*)alloc((size_t)BT_*U_*2);
  float*          c     = (float*)alloc((size_t)B_*U_*4);
  unsigned short* hb0   = (unsigned short*)alloc((size_t)B_*U_*2);
  unsigned short* hb1   = (unsigned short*)alloc((size_t)B_*U_*2);
  unsigned short* ctxb  = (unsigned short*)alloc((size_t)B_*U_*2);
  float*          tq    = (float*)alloc((size_t)B_*U_*4);
  float*          scores= (float*)alloc((size_t)B_*T_*4);
  float*          zh    = (float*)alloc((size_t)4*U_*64*4);
  float*          out_part = (float*)alloc((size_t)64*256*4);
  unsigned*       cnt   = (unsigned*)alloc(64*32*4);
  unsigned*       rel   = (unsigned*)alloc(64*32*4);
  if (ws_size < off) return;  // workspace too small: fail loudly (validation mismatch)

  init_kernel<<<256, 256, 0, stream>>>(c, hb0, hb1, cnt, rel);
  transpose_bf_kernel<<<(128/32)*(1024/32),  256, 0, stream>>>(We1, We1Tb, 128, 1024);
  transpose_bf_kernel<<<(1024/32)*(1024/32), 256, 0, stream>>>(We2, We2Tb, 1024, 1024);
  transpose_bf_kernel<<<(1024/32)*(1024/32), 256, 0, stream>>>(W2,  W2Tb,  1024, 1024);
  transpose_bf_kernel<<<(1024/32)*(1024/32), 256, 0, stream>>>(W1,  W1Tb,  1024, 1024);
  transpose_bf_kernel<<<(1024/32)*(4096/32), 256, 0, stream>>>(Wk,  WkTb,  1024, 4096);
  transpose_bf_kernel<<<(1024/32)*(4096/32), 256, 0, stream>>>(Wr,  WrTb,  1024, 4096);

  gemm_embed<1><<<4096, 256, 0, stream>>>((const void*)inputs, We1Tb, be1, h1tk, DIN_, 0);
  gemm_embed<0><<<4096, 256, 0, stream>>>((const void*)h1tk,   We2Tb, be2, xv,   U_,   0);
  gemm_embed<0><<<4096, 256, 0, stream>>>((const void*)xv,     W2Tb,  b2,  h1tk, U_,   1);

  SeqP sp;
  sp.W1Tb = W1Tb; sp.WkTb = WkTb; sp.WrTb = WrTb; sp.tk = h1tk; sp.xv = xv;
  sp.b1 = b1; sp.bl = bl; sp.V = V; sp.Wo = Wo; sp.bo = bo;
  sp.tq = tq; sp.scores = scores; sp.c = c; sp.zh = zh;
  sp.out_part = out_part; sp.out = out;
  sp.ctxb = ctxb; sp.hb0 = hb0; sp.hb1 = hb1; sp.cnt = cnt; sp.rel = rel;
  // Plain launch: co-residency (2 blocks/CU for 512 blocks on 256 CUs) is
  // guaranteed by __launch_bounds__(256,2) resource caps, not by the
  // cooperative-launch validator (which rejected grids > 256 in rounds 2-4).
  seq_kernel<<<dim3(G_), dim3(256), 0, stream>>>(sp);
}

// Round 6
// 18108.531 us; speedup vs baseline: 1.9928x; 1.7946x over previous
//
#include <hip/hip_runtime.h>

#define U_ 1024
#define B_ 64
#define T_ 256
#define DIN_ 128
#define BT_ (B_*T_)
#define G_ 512   // seq kernel grid: 2 blocks/CU by launch_bounds(256,2); plain launch (coop validator rejects >256)

typedef __attribute__((ext_vector_type(4))) float f32x4;
typedef __attribute__((ext_vector_type(8))) short s16x8;
typedef __attribute__((ext_vector_type(4))) unsigned short u16x4;
typedef unsigned long long u64;

union U64F2 { u64 q; float f[2]; };
union U64H4 { u64 q; unsigned short h[4]; };

__device__ inline unsigned short f2bf(float x){
  unsigned u = __float_as_uint(x);
  u += 0x7FFFu + ((u >> 16) & 1u);
  return (unsigned short)(u >> 16);
}
__device__ inline float bf2f(unsigned short b){ return __uint_as_float(((unsigned)b) << 16); }
__device__ inline float fast_rcp(float x){ return __builtin_amdgcn_rcpf(x); }
__device__ inline float fast_tanh(float x){
  float e = __expf(2.0f * x);
  return 1.0f - 2.0f * fast_rcp(e + 1.0f);
}
__device__ inline float fast_sig(float x){
  return fast_rcp(1.0f + __expf(-x));
}

// sc1 (agent-coherent, L3-point) accessors — no fences anywhere.
__device__ inline u64 ald64(const u64* p){
  return __hip_atomic_load((u64*)p, __ATOMIC_RELAXED, __HIP_MEMORY_SCOPE_AGENT);
}
__device__ inline void ast64(u64* p, u64 v){
  __hip_atomic_store(p, v, __ATOMIC_RELAXED, __HIP_MEMORY_SCOPE_AGENT);
}
__device__ inline float aldf(const float* p){
  return __hip_atomic_load((float*)p, __ATOMIC_RELAXED, __HIP_MEMORY_SCOPE_AGENT);
}
__device__ inline void astf(float* p, float v){
  __hip_atomic_store(p, v, __ATOMIC_RELAXED, __HIP_MEMORY_SCOPE_AGENT);
}
__device__ inline s16x8 frag_ald(const u64* p){
  u64 a = ald64(p), b = ald64(p + 1);
  union { u64 q[2]; s16x8 v; } x; x.q[0] = a; x.q[1] = b; return x.v;
}

// ---------------- init: zero state + barrier lines, compute softmax shift bound ----------------
__global__ void init_kernel(float* c, unsigned short* hb0, unsigned short* hb1,
                            unsigned* cnt, const float* V, float* vbound){
  int i = blockIdx.x * 256 + threadIdx.x;
  if (i < B_*U_){ c[i] = 0.f; hb0[i] = 0; hb1[i] = 0; }
  if (i < 64*16) cnt[i] = 0u;
  if (blockIdx.x == 0){
    __shared__ float red[4];
    int t = threadIdx.x, lane = t & 63, w = t >> 6;
    float s = fabsf(V[t]) + fabsf(V[t+256]) + fabsf(V[t+512]) + fabsf(V[t+768]);
    #pragma unroll
    for (int mk = 32; mk >= 1; mk >>= 1) s += __shfl_xor(s, mk, 64);
    if (lane == 0) red[w] = s;
    __syncthreads();
    if (t == 0) vbound[0] = red[0] + red[1] + red[2] + red[3];
  }
}

// ---------------- transpose + bf16 convert: W[K][N] -> WT[N][K] ----------------
__global__ void transpose_bf_kernel(const float* W, unsigned short* WT, int K, int N){
  int ktiles = K >> 5;
  int kb = blockIdx.x % ktiles, nb = blockIdx.x / ktiles;
  __shared__ float tile[32][33];
  int x = threadIdx.x & 31, y8 = threadIdx.x >> 5;
  #pragma unroll
  for (int i = 0; i < 4; ++i){
    int y = y8*4 + i;
    tile[y][x] = W[(size_t)(kb*32 + y)*N + nb*32 + x];
  }
  __syncthreads();
  #pragma unroll
  for (int i = 0; i < 4; ++i){
    int y = y8*4 + i;
    WT[(size_t)(nb*32 + y)*K + kb*32 + x] = f2bf(tile[x][y]);
  }
}

// ---------------- embedding GEMMs (once per launch) ----------------
template<int AF32>
__global__ __launch_bounds__(256) void gemm_embed(const void* Aptr, const unsigned short* BT,
                                                  const float* bias, unsigned short* Cout,
                                                  int K, int act){
  int nb = blockIdx.x & 15, mb = blockIdx.x >> 4;
  int lane = threadIdx.x & 63, w = threadIdx.x >> 6;
  int l15 = lane & 15, quad = lane >> 4;
  int m0 = mb*64 + w*16;
  int arow = m0 + l15;
  f32x4 acc[4];
  #pragma unroll
  for (int nt = 0; nt < 4; ++nt) acc[nt] = (f32x4){0.f,0.f,0.f,0.f};

  for (int k0 = 0; k0 < K; k0 += 32){
    int koff = k0 + quad*8;
    s16x8 a8;
    if (AF32){
      const float* ap = (const float*)Aptr + (size_t)arow*K + koff;
      f32x4 lo = *(const f32x4*)ap;
      f32x4 hi = *(const f32x4*)(ap + 4);
      a8[0]=(short)f2bf(lo[0]); a8[1]=(short)f2bf(lo[1]); a8[2]=(short)f2bf(lo[2]); a8[3]=(short)f2bf(lo[3]);
      a8[4]=(short)f2bf(hi[0]); a8[5]=(short)f2bf(hi[1]); a8[6]=(short)f2bf(hi[2]); a8[7]=(short)f2bf(hi[3]);
    } else {
      a8 = *(const s16x8*)((const unsigned short*)Aptr + (size_t)arow*K + koff);
    }
    #pragma unroll
    for (int nt = 0; nt < 4; ++nt){
      const unsigned short* bp = BT + (size_t)(nb*64 + nt*16 + l15)*K + koff;
      s16x8 b8 = *(const s16x8*)bp;
      acc[nt] = __builtin_amdgcn_mfma_f32_16x16x32_bf16(a8, b8, acc[nt], 0, 0, 0);
    }
  }
  #pragma unroll
  for (int nt = 0; nt < 4; ++nt){
    int col = nb*64 + nt*16 + l15;
    float bv = bias[col];
    #pragma unroll
    for (int r = 0; r < 4; ++r){
      int row = m0 + quad*4 + r;
      float v = acc[nt][r] + bv;
      v = (act == 0) ? fmaxf(v, 0.f) : fast_tanh(v);
      Cout[(size_t)row*U_ + col] = f2bf(v);
    }
  }
}

// ---------------- persistent sequential kernel ----------------
struct SeqP {
  const unsigned short *W1Tb, *WkTb, *WrTb, *tk, *xv;
  const float *b1, *bl, *V, *Wo, *bo, *vbound;
  float *tq, *ew, *c, *zh, *out_part, *out;
  unsigned short *ctxb, *hb0, *hb1;
  unsigned *cnt;
};

// One-hop flush-free barrier: arrive = 1 sc1 add to 1-of-64 64B-spaced lines;
// observe = wave 0 loads all 64 lines (sc1) lane-parallel + shuffle-sum.
// No __threadfence (avoids per-block buffer_wbl2/inv L2 flushes): ordering comes
// from __syncthreads' vmcnt(0) drain (sc1 store acks are from L3) before the add.
__device__ inline void gridbar(unsigned* cnt, unsigned barno){
  __syncthreads();   // all waves' sc1 stores acked at L3 before arrive
  if (threadIdx.x == 0)
    __hip_atomic_fetch_add(&cnt[(blockIdx.x & 63) * 16], 1u, __ATOMIC_RELAXED, __HIP_MEMORY_SCOPE_AGENT);
  if (threadIdx.x < 64){
    const unsigned tgt = barno * G_;
    for (;;){
      unsigned v = __hip_atomic_load(&cnt[threadIdx.x * 16], __ATOMIC_RELAXED, __HIP_MEMORY_SCOPE_AGENT);
      #pragma unroll
      for (int mk = 32; mk >= 1; mk >>= 1) v += __shfl_xor(v, mk, 64);
      if (v >= tgt) break;
      __builtin_amdgcn_s_sleep(2);
    }
  }
  __syncthreads();   // holds other waves until wave 0 observed
}

__device__ inline void out_reduce(const SeqP& p, int b, int sidx, float* smem,
                                  int t, int lane, int w){
  float v = aldf(&p.out_part[b*256 + t]);
  #pragma unroll
  for (int mk = 32; mk >= 1; mk >>= 1) v += __shfl_xor(v, mk, 64);
  if (lane == 0) smem[w] = v;
  __syncthreads();
  if (t == 0) p.out[sidx*64 + b] = smem[0] + smem[1] + smem[2] + smem[3] + p.bo[0];
  __syncthreads();
}

__global__ __launch_bounds__(256, 2) void seq_kernel(SeqP p){
  const int bi = blockIdx.x;
  const int t  = threadIdx.x;
  const int lane = t & 63, w = t >> 6;
  const int l15 = lane & 15, quad = lane >> 4;
  __shared__ __align__(16) float smem[1664];
  unsigned barno = 0;
  const float Mb = p.vbound[0];   // softmax shift bound: |score| < sum|V|

  u64* tqu  = (u64*)p.tq;
  u64* ewu  = (u64*)p.ew;
  u64* zhu  = (u64*)p.zh;
  u64* ctxu = (u64*)p.ctxb;

  for (int step = 0; step < T_; ++step){
    const u64* hbRu = (const u64*)((step & 1) ? p.hb1 : p.hb0);
    u64*       hbWu = (u64*)((step & 1) ? p.hb0 : p.hb1);

    gridbar(p.cnt, ++barno);   // h_{t-1}, out_part at L3

    // ---- Phase A: tq (blocks 0..63), zh = h@Wr + bl (blocks 64..191),
    //               out reduction for step-1 (blocks 448..511) ----
    if (bi < 64){
      int jcol = bi*16 + l15;
      int rbase = (w*16 + l15) << 8;           // row * 1024 shorts / 4 = row * 256 u64
      const unsigned short* bp = p.W1Tb + (size_t)jcol*U_;
      f32x4 acc = (f32x4){0.f,0.f,0.f,0.f};
      #pragma unroll 8
      for (int k = 0; k < U_; k += 32){
        s16x8 a8 = frag_ald(hbRu + rbase + ((k + quad*8) >> 2));
        s16x8 b8 = *(const s16x8*)(bp + k + quad*8);
        acc = __builtin_amdgcn_mfma_f32_16x16x32_bf16(a8, b8, acc, 0, 0, 0);
      }
      float bj = p.b1[jcol];
      float* tqs = smem;   // 16*68
      #pragma unroll
      for (int r = 0; r < 4; ++r)
        tqs[l15*68 + w*16 + quad*4 + r] = fast_tanh(acc[r] + bj);
      __syncthreads();
      if (t < 64){
        int ub64 = (t*U_ + bi*16) >> 1;        // float-pair index
        #pragma unroll
        for (int cc = 0; cc < 16; cc += 2){
          U64F2 x;
          x.f[0] = tqs[(cc+0)*68 + t];
          x.f[1] = tqs[(cc+1)*68 + t];
          ast64(tqu + ub64 + (cc >> 1), x.q);
        }
      }
    } else if (bi < 192){
      int bz = bi - 64;    // 32 cols each
      int rbase = (w*16 + l15) << 8;
      int jc0 = bz*32 + l15, jc1 = jc0 + 16;
      const unsigned short* bp0 = p.WrTb + (size_t)jc0*U_;
      const unsigned short* bp1 = p.WrTb + (size_t)jc1*U_;
      f32x4 acc0 = (f32x4){0.f,0.f,0.f,0.f}, acc1 = acc0;
      #pragma unroll 8
      for (int k = 0; k < U_; k += 32){
        s16x8 a8 = frag_ald(hbRu + rbase + ((k + quad*8) >> 2));
        acc0 = __builtin_amdgcn_mfma_f32_16x16x32_bf16(a8, *(const s16x8*)(bp0 + k + quad*8), acc0, 0, 0, 0);
        acc1 = __builtin_amdgcn_mfma_f32_16x16x32_bf16(a8, *(const s16x8*)(bp1 + k + quad*8), acc1, 0, 0, 0);
      }
      float bl0 = p.bl[jc0], bl1 = p.bl[jc1];
      int brow = w*16 + quad*4;
      U64F2 x;
      int i0 = (jc0*64 + brow) >> 1;
      x.f[0] = acc0[0] + bl0; x.f[1] = acc0[1] + bl0; ast64(zhu + i0, x.q);
      x.f[0] = acc0[2] + bl0; x.f[1] = acc0[3] + bl0; ast64(zhu + i0 + 1, x.q);
      int i1 = (jc1*64 + brow) >> 1;
      x.f[0] = acc1[0] + bl1; x.f[1] = acc1[1] + bl1; ast64(zhu + i1, x.q);
      x.f[0] = acc1[2] + bl1; x.f[1] = acc1[3] + bl1; ast64(zhu + i1 + 1, x.q);
    } else if (bi >= 448){
      if (step > 0) out_reduce(p, bi - 448, step - 1, smem, t, lane, w);
    }

    gridbar(p.cnt, ++barno);   // tq, zh at L3

    // ---- Phase B1: ew[b][t] = exp(score - Mb), all 512 blocks ----
    {
      int b = bi >> 3, tg = bi & 7;
      float tqv[16], Vv[16];
      int tqb = (b*U_ + lane*16) >> 1;
      #pragma unroll
      for (int i = 0; i < 8; ++i){
        U64F2 x; x.q = ald64(tqu + tqb + i);
        tqv[2*i] = x.f[0]; tqv[2*i+1] = x.f[1];
      }
      const float* Vp = p.V + lane*16;
      #pragma unroll
      for (int i = 0; i < 16; i += 4) *(f32x4*)&Vv[i] = *(const f32x4*)(Vp + i);
      int trow = tg*32 + w*8;
      const unsigned short* kp = p.tk + (size_t)(b*T_ + trow)*U_ + lane*16;
      float sr[8];
      #pragma unroll
      for (int rr = 0; rr < 8; ++rr){
        s16x8 k0 = *(const s16x8*)(kp + (size_t)rr*U_);
        s16x8 k1 = *(const s16x8*)(kp + (size_t)rr*U_ + 8);
        float s = 0.f;
        #pragma unroll
        for (int e = 0; e < 8; ++e){
          float kf = bf2f((unsigned short)k0[e]);
          float num = tqv[e] + kf;
          float den = fmaf(tqv[e], kf, 1.0f);
          s += Vv[e] * num * fast_rcp(den);
        }
        #pragma unroll
        for (int e = 0; e < 8; ++e){
          float kf = bf2f((unsigned short)k1[e]);
          float num = tqv[8+e] + kf;
          float den = fmaf(tqv[8+e], kf, 1.0f);
          s += Vv[8+e] * num * fast_rcp(den);
        }
        sr[rr] = s;
      }
      #pragma unroll
      for (int mk = 32; mk >= 1; mk >>= 1){
        #pragma unroll
        for (int rr = 0; rr < 8; ++rr) sr[rr] += __shfl_xor(sr[rr], mk, 64);
      }
      if (lane == 0){
        int eb = (b*T_ + trow) >> 1;
        #pragma unroll
        for (int j = 0; j < 4; ++j){
          U64F2 x;
          x.f[0] = __expf(sr[2*j]   - Mb);
          x.f[1] = __expf(sr[2*j+1] - Mb);
          ast64(ewu + eb + j, x.q);
        }
      }
    }

    gridbar(p.cnt, ++barno);   // ew at L3

    // ---- Phase B2: denom + weighted ctx chunk, b = bi>>3, 128 u's ----
    {
      int b = bi >> 3, ug = bi & 7;
      float* ewL = smem;        // 256
      float* tmp = smem + 256;  // 16
      float* red = smem + 272;  // 8*32*4 = 1024
      if (t < 128){
        U64F2 x; x.q = ald64(ewu + b*128 + t);
        ewL[2*t] = x.f[0]; ewL[2*t+1] = x.f[1];
      }
      __syncthreads();
      float e = ewL[t];
      float sum = e;
      #pragma unroll
      for (int mk = 32; mk >= 1; mk >>= 1) sum += __shfl_xor(sum, mk, 64);
      if (lane == 0) tmp[w] = sum;
      __syncthreads();
      float rd = fast_rcp(tmp[0] + tmp[1] + tmp[2] + tmp[3]);

      int ui = t & 31, tgp = t >> 5;
      int u = ug*128 + ui*4;
      const unsigned short* xp = p.xv + (size_t)b*T_*U_ + u;
      f32x4 a = (f32x4){0.f,0.f,0.f,0.f};
      for (int t8 = tgp; t8 < T_; t8 += 8){
        float wg = ewL[t8];
        u16x4 x4 = *(const u16x4*)(xp + (size_t)t8*U_);
        a[0] = fmaf(wg, bf2f(x4[0]), a[0]);
        a[1] = fmaf(wg, bf2f(x4[1]), a[1]);
        a[2] = fmaf(wg, bf2f(x4[2]), a[2]);
        a[3] = fmaf(wg, bf2f(x4[3]), a[3]);
      }
      *(f32x4*)&red[(tgp*32 + ui)*4] = a;
      __syncthreads();
      if (t < 32){
        f32x4 r = (f32x4){0.f,0.f,0.f,0.f};
        #pragma unroll
        for (int g = 0; g < 8; ++g){
          f32x4 rr = *(f32x4*)&red[(g*32 + t)*4];
          r[0]+=rr[0]; r[1]+=rr[1]; r[2]+=rr[2]; r[3]+=rr[3];
        }
        U64H4 cv;
        cv.h[0]=f2bf(r[0]*rd); cv.h[1]=f2bf(r[1]*rd); cv.h[2]=f2bf(r[2]*rd); cv.h[3]=f2bf(r[3]*rd);
        ast64(ctxu + b*256 + ug*32 + t, cv.q);
      }
    }

    gridbar(p.cnt, ++barno);   // ctxb at L3

    // ---- Phase C: z = ctx@Wk + zh, LSTM update (blocks 0..255, 4 u's each) ----
    if (bi < 256){
      int ub = bi*4;
      int gate = l15 >> 2, uo = l15 & 3;
      int jcol = gate*U_ + ub + uo;
      int rbase = (w*16 + l15) << 8;
      const unsigned short* bp0 = p.WkTb + (size_t)jcol*U_;
      f32x4 acc = (f32x4){0.f,0.f,0.f,0.f};
      #pragma unroll 8
      for (int k = 0; k < U_; k += 32){
        s16x8 a8 = frag_ald(ctxu + rbase + ((k + quad*8) >> 2));
        acc = __builtin_amdgcn_mfma_f32_16x16x32_bf16(a8, *(const s16x8*)(bp0 + k + quad*8), acc, 0, 0, 0);
      }
      int brow = w*16 + quad*4;
      int zi0 = (jcol*64 + brow) >> 1;
      U64F2 z0, z1;
      z0.q = ald64(zhu + zi0); z1.q = ald64(zhu + zi0 + 1);
      acc[0] += z0.f[0]; acc[1] += z0.f[1]; acc[2] += z1.f[0]; acc[3] += z1.f[1];
      float* zs = smem;          // 16*68 = 1088
      float* hs = smem + 1088;   // 256
      float* op = smem + 1344;   // 256
      *(f32x4*)&zs[l15*68 + brow] = acc;
      __syncthreads();
      {
        int b = t & 63, ui = t >> 6;   // ui in 0..3
        int u = ub + ui;
        float zi = zs[(0*4 + ui)*68 + b];
        float zf = zs[(1*4 + ui)*68 + b];
        float zg = zs[(2*4 + ui)*68 + b];
        float zo = zs[(3*4 + ui)*68 + b];
        float ig = fast_sig(zi), fg = fast_sig(zf);
        float gg = fast_tanh(zg), og = fast_sig(zo);
        float cold = p.c[u*64 + b];    // c is block-private: plain, stays in local L2
        float cn = fg*cold + ig*gg;
        float hn = og * fast_tanh(cn);
        p.c[u*64 + b] = cn;
        hs[ui*64 + b] = hn;
        op[ui*64 + b] = hn * p.Wo[u];
      }
      __syncthreads();
      if (t < 64){
        U64H4 h0;
        #pragma unroll
        for (int k = 0; k < 4; ++k) h0.h[k] = f2bf(hs[k*64 + t]);
        ast64(hbWu + t*256 + bi, h0.q);
        float po = op[t] + op[64 + t] + op[128 + t] + op[192 + t];
        astf(&p.out_part[t*256 + bi], po);
      }
    }
  }

  gridbar(p.cnt, ++barno);   // final out_part at L3
  if (bi >= 448) out_reduce(p, bi - 448, T_ - 1, smem, t, lane, w);
}

extern "C" void kernel_launch(void* const* d_in, const int* in_sizes, int n_in,
                              void* d_out, int out_size, void* d_ws, size_t ws_size,
                              hipStream_t stream){
  const float* inputs = (const float*)d_in[0];
  const float* We1 = (const float*)d_in[1];
  const float* be1 = (const float*)d_in[2];
  const float* We2 = (const float*)d_in[3];
  const float* be2 = (const float*)d_in[4];
  const float* W1  = (const float*)d_in[5];
  const float* b1  = (const float*)d_in[6];
  const float* W2  = (const float*)d_in[7];
  const float* b2  = (const float*)d_in[8];
  const float* V   = (const float*)d_in[9];
  // d_in[10] = bV: softmax shift-invariant, dropped
  const float* Wk  = (const float*)d_in[11];
  const float* Wr  = (const float*)d_in[12];
  const float* bl  = (const float*)d_in[13];
  const float* Wo  = (const float*)d_in[14];
  const float* bo  = (const float*)d_in[15];
  float* out = (float*)d_out;

  char* ws = (char*)d_ws;
  size_t off = 0;
  auto alloc = [&](size_t bytes) -> void* {
    void* pp = ws + off;
    off = (off + bytes + 255) & ~(size_t)255;
    return pp;
  };
  // h1 (GEMM-1 output) is dead after GEMM-2; tk (GEMM-3 output) aliases it.
  unsigned short* We1Tb = (unsigned short*)alloc((size_t)1024*128*2);
  unsigned short* We2Tb = (unsigned short*)alloc((size_t)1024*1024*2);
  unsigned short* W2Tb  = (unsigned short*)alloc((size_t)1024*1024*2);
  unsigned short* W1Tb  = (unsigned short*)alloc((size_t)1024*1024*2);
  unsigned short* WkTb  = (unsigned short*)alloc((size_t)4096*1024*2);
  unsigned short* WrTb  = (unsigned short*)alloc((size_t)4096*1024*2);
  unsigned short* h1tk  = (unsigned short*)alloc((size_t)BT_*U_*2);  // h1, then tk
  unsigned short* xv    = (unsigned short*)alloc((size_t)BT_*U_*2);
  float*          c     = (float*)alloc((size_t)B_*U_*4);
  unsigned short* hb0   = (unsigned short*)alloc((size_t)B_*U_*2);
  unsigned short* hb1   = (unsigned short*)alloc((size_t)B_*U_*2);
  unsigned short* ctxb  = (unsigned short*)alloc((size_t)B_*U_*2);
  float*          tq    = (float*)alloc((size_t)B_*U_*4);
  float*          ew    = (float*)alloc((size_t)B_*T_*4);
  float*          zh    = (float*)alloc((size_t)4*U_*64*4);
  float*          out_part = (float*)alloc((size_t)64*256*4);
  unsigned*       cnt   = (unsigned*)alloc(64*16*4);
  float*          vbound= (float*)alloc(256);
  if (ws_size < off) return;  // workspace too small: fail loudly (validation mismatch)

  init_kernel<<<256, 256, 0, stream>>>(c, hb0, hb1, cnt, V, vbound);
  transpose_bf_kernel<<<(128/32)*(1024/32),  256, 0, stream>>>(We1, We1Tb, 128, 1024);
  transpose_bf_kernel<<<(1024/32)*(1024/32), 256, 0, stream>>>(We2, We2Tb, 1024, 1024);
  transpose_bf_kernel<<<(1024/32)*(1024/32), 256, 0, stream>>>(W2,  W2Tb,  1024, 1024);
  transpose_bf_kernel<<<(1024/32)*(1024/32), 256, 0, stream>>>(W1,  W1Tb,  1024, 1024);
  transpose_bf_kernel<<<(1024/32)*(4096/32), 256, 0, stream>>>(Wk,  WkTb,  1024, 4096);
  transpose_bf_kernel<<<(1024/32)*(4096/32), 256, 0, stream>>>(Wr,  WrTb,  1024, 4096);

  gemm_embed<1><<<4096, 256, 0, stream>>>((const void*)inputs, We1Tb, be1, h1tk, DIN_, 0);
  gemm_embed<0><<<4096, 256, 0, stream>>>((const void*)h1tk,   We2Tb, be2, xv,   U_,   0);
  gemm_embed<0><<<4096, 256, 0, stream>>>((const void*)xv,     W2Tb,  b2,  h1tk, U_,   1);

  SeqP sp;
  sp.W1Tb = W1Tb; sp.WkTb = WkTb; sp.WrTb = WrTb; sp.tk = h1tk; sp.xv = xv;
  sp.b1 = b1; sp.bl = bl; sp.V = V; sp.Wo = Wo; sp.bo = bo; sp.vbound = vbound;
  sp.tq = tq; sp.ew = ew; sp.c = c; sp.zh = zh;
  sp.out_part = out_part; sp.out = out;
  sp.ctxb = ctxb; sp.hb0 = hb0; sp.hb1 = hb1; sp.cnt = cnt;
  seq_kernel<<<dim3(G_), dim3(256), 0, stream>>>(sp);
}

// Round 7
// 15014.067 us; speedup vs baseline: 2.4035x; 1.2061x over previous
//
#include <hip/hip_runtime.h>

#define U_ 1024
#define B_ 64
#define T_ 256
#define DIN_ 128
#define BT_ (B_*T_)
#define G_ 1024  // 4 blocks/CU resident by launch_bounds(256,4); plain launch (coop validator rejects >256)

typedef __attribute__((ext_vector_type(4))) float f32x4;
typedef __attribute__((ext_vector_type(8))) short s16x8;
typedef __attribute__((ext_vector_type(4))) unsigned short u16x4;
typedef unsigned long long u64;

union U64F2 { u64 q; float f[2]; };
union U64H4 { u64 q; unsigned short h[4]; };

__device__ inline unsigned short f2bf(float x){
  unsigned u = __float_as_uint(x);
  u += 0x7FFFu + ((u >> 16) & 1u);
  return (unsigned short)(u >> 16);
}
__device__ inline float bf2f(unsigned short b){ return __uint_as_float(((unsigned)b) << 16); }
__device__ inline float fast_rcp(float x){ return __builtin_amdgcn_rcpf(x); }
__device__ inline float fast_tanh(float x){
  float e = __expf(2.0f * x);
  return 1.0f - 2.0f * fast_rcp(e + 1.0f);
}
__device__ inline float fast_sig(float x){
  return fast_rcp(1.0f + __expf(-x));
}

// sc1 (agent-coherent, L3-point) accessors — no fences anywhere.
__device__ inline u64 ald64(const u64* p){
  return __hip_atomic_load((u64*)p, __ATOMIC_RELAXED, __HIP_MEMORY_SCOPE_AGENT);
}
__device__ inline void ast64(u64* p, u64 v){
  __hip_atomic_store(p, v, __ATOMIC_RELAXED, __HIP_MEMORY_SCOPE_AGENT);
}
__device__ inline float aldf(const float* p){
  return __hip_atomic_load((float*)p, __ATOMIC_RELAXED, __HIP_MEMORY_SCOPE_AGENT);
}
__device__ inline void astf(float* p, float v){
  __hip_atomic_store(p, v, __ATOMIC_RELAXED, __HIP_MEMORY_SCOPE_AGENT);
}
__device__ inline s16x8 frag_ald(const u64* p){
  u64 a = ald64(p), b = ald64(p + 1);
  union { u64 q[2]; s16x8 v; } x; x.q[0] = a; x.q[1] = b; return x.v;
}

// ---------------- init: zero state + barrier lines, compute softmax shift bound ----------------
__global__ void init_kernel(float* c, unsigned short* hb0, unsigned short* hb1,
                            unsigned* cnt, unsigned* rel, const float* V, float* vbound){
  int i = blockIdx.x * 256 + threadIdx.x;
  if (i < B_*U_){ c[i] = 0.f; hb0[i] = 0; hb1[i] = 0; }
  if (i < 64*16){ cnt[i] = 0u; rel[i] = 0u; }
  if (blockIdx.x == 0){
    __shared__ float red[4];
    int t = threadIdx.x, lane = t & 63, w = t >> 6;
    float s = fabsf(V[t]) + fabsf(V[t+256]) + fabsf(V[t+512]) + fabsf(V[t+768]);
    #pragma unroll
    for (int mk = 32; mk >= 1; mk >>= 1) s += __shfl_xor(s, mk, 64);
    if (lane == 0) red[w] = s;
    __syncthreads();
    if (t == 0) vbound[0] = red[0] + red[1] + red[2] + red[3];
  }
}

// ---------------- transpose + bf16 convert: W[K][N] -> WT[N][K] ----------------
__global__ void transpose_bf_kernel(const float* W, unsigned short* WT, int K, int N){
  int ktiles = K >> 5;
  int kb = blockIdx.x % ktiles, nb = blockIdx.x / ktiles;
  __shared__ float tile[32][33];
  int x = threadIdx.x & 31, y8 = threadIdx.x >> 5;
  #pragma unroll
  for (int i = 0; i < 4; ++i){
    int y = y8*4 + i;
    tile[y][x] = W[(size_t)(kb*32 + y)*N + nb*32 + x];
  }
  __syncthreads();
  #pragma unroll
  for (int i = 0; i < 4; ++i){
    int y = y8*4 + i;
    WT[(size_t)(nb*32 + y)*K + kb*32 + x] = f2bf(tile[x][y]);
  }
}

// ---------------- embedding GEMMs (once per launch) ----------------
template<int AF32>
__global__ __launch_bounds__(256) void gemm_embed(const void* Aptr, const unsigned short* BT,
                                                  const float* bias, unsigned short* Cout,
                                                  int K, int act){
  int nb = blockIdx.x & 15, mb = blockIdx.x >> 4;
  int lane = threadIdx.x & 63, w = threadIdx.x >> 6;
  int l15 = lane & 15, quad = lane >> 4;
  int m0 = mb*64 + w*16;
  int arow = m0 + l15;
  f32x4 acc[4];
  #pragma unroll
  for (int nt = 0; nt < 4; ++nt) acc[nt] = (f32x4){0.f,0.f,0.f,0.f};

  for (int k0 = 0; k0 < K; k0 += 32){
    int koff = k0 + quad*8;
    s16x8 a8;
    if (AF32){
      const float* ap = (const float*)Aptr + (size_t)arow*K + koff;
      f32x4 lo = *(const f32x4*)ap;
      f32x4 hi = *(const f32x4*)(ap + 4);
      a8[0]=(short)f2bf(lo[0]); a8[1]=(short)f2bf(lo[1]); a8[2]=(short)f2bf(lo[2]); a8[3]=(short)f2bf(lo[3]);
      a8[4]=(short)f2bf(hi[0]); a8[5]=(short)f2bf(hi[1]); a8[6]=(short)f2bf(hi[2]); a8[7]=(short)f2bf(hi[3]);
    } else {
      a8 = *(const s16x8*)((const unsigned short*)Aptr + (size_t)arow*K + koff);
    }
    #pragma unroll
    for (int nt = 0; nt < 4; ++nt){
      const unsigned short* bp = BT + (size_t)(nb*64 + nt*16 + l15)*K + koff;
      s16x8 b8 = *(const s16x8*)bp;
      acc[nt] = __builtin_amdgcn_mfma_f32_16x16x32_bf16(a8, b8, acc[nt], 0, 0, 0);
    }
  }
  #pragma unroll
  for (int nt = 0; nt < 4; ++nt){
    int col = nb*64 + nt*16 + l15;
    float bv = bias[col];
    #pragma unroll
    for (int r = 0; r < 4; ++r){
      int row = m0 + quad*4 + r;
      float v = acc[nt][r] + bv;
      v = (act == 0) ? fmaxf(v, 0.f) : fast_tanh(v);
      Cout[(size_t)row*U_ + col] = f2bf(v);
    }
  }
}

// ---------------- persistent sequential kernel ----------------
struct SeqP {
  const unsigned short *W1Tb, *WkTb, *WrTb, *tk, *xv;
  const float *b1, *bl, *V, *Wo, *bo, *vbound;
  float *tq, *ew, *c, *zh, *out_part, *out;
  unsigned short *ctxb, *hb0, *hb1;
  unsigned *cnt, *rel;
};

// Hierarchical flush-free barrier: arrive = 1 sc1 add to 1-of-64 64B-spaced
// lines; block 0's wave 0 gathers all 64 (lane-parallel), then releases 64
// lines; every other block polls ONE line. ~1K poll loads/round grid-wide
// (round-6's flat barrier: 32K loads/round hammering the same 64 lines).
// No __threadfence: ordering from __syncthreads' vmcnt(0) drain (sc1 store
// acks from L3) before the arrive-add; consumers use sc1 loads.
__device__ inline void gridbar(unsigned* cnt, unsigned* rel, unsigned barno){
  __syncthreads();
  if (threadIdx.x == 0)
    __hip_atomic_fetch_add(&cnt[(blockIdx.x & 63) * 16], 1u, __ATOMIC_RELAXED, __HIP_MEMORY_SCOPE_AGENT);
  if (blockIdx.x == 0){
    if (threadIdx.x < 64){
      const unsigned tgt = barno * G_;
      for (;;){
        unsigned v = __hip_atomic_load(&cnt[threadIdx.x * 16], __ATOMIC_RELAXED, __HIP_MEMORY_SCOPE_AGENT);
        #pragma unroll
        for (int mk = 32; mk >= 1; mk >>= 1) v += __shfl_xor(v, mk, 64);
        if (v >= tgt) break;
        __builtin_amdgcn_s_sleep(2);
      }
      __hip_atomic_store(&rel[threadIdx.x * 16], barno, __ATOMIC_RELAXED, __HIP_MEMORY_SCOPE_AGENT);
    }
  } else if (threadIdx.x == 0){
    unsigned* myrel = &rel[(blockIdx.x & 63) * 16];
    while (__hip_atomic_load(myrel, __ATOMIC_RELAXED, __HIP_MEMORY_SCOPE_AGENT) < barno)
      __builtin_amdgcn_s_sleep(4);
  }
  __syncthreads();
}

__device__ inline void out_reduce(const SeqP& p, int b, int sidx, float* smem,
                                  int t, int lane, int w){
  float v = aldf(&p.out_part[b*256 + t]);
  #pragma unroll
  for (int mk = 32; mk >= 1; mk >>= 1) v += __shfl_xor(v, mk, 64);
  if (lane == 0) smem[w] = v;
  __syncthreads();
  if (t == 0) p.out[sidx*64 + b] = smem[0] + smem[1] + smem[2] + smem[3] + p.bo[0];
  __syncthreads();
}

__global__ __launch_bounds__(256, 4) void seq_kernel(SeqP p){
  const int bi = blockIdx.x;
  const int t  = threadIdx.x;
  const int lane = t & 63, w = t >> 6;
  const int l15 = lane & 15, quad = lane >> 4;
  __shared__ __align__(16) float smem[1664];
  unsigned barno = 0;
  const float Mb = p.vbound[0];   // softmax shift bound: |score| < sum|V|

  u64* tqu  = (u64*)p.tq;
  u64* ewu  = (u64*)p.ew;
  u64* zhu  = (u64*)p.zh;
  u64* ctxu = (u64*)p.ctxb;

  for (int step = 0; step < T_; ++step){
    const u64* hbRu = (const u64*)((step & 1) ? p.hb1 : p.hb0);
    u64*       hbWu = (u64*)((step & 1) ? p.hb0 : p.hb1);

    gridbar(p.cnt, p.rel, ++barno);   // h_{t-1}, out_part at L3

    // ---- Phase A: tq (blocks 0..63), zh = h@Wr + bl (blocks 64..319, 16 cols each),
    //               out reduction for step-1 (blocks 960..1023) ----
    if (bi < 64){
      int jcol = bi*16 + l15;
      int rbase = (w*16 + l15) << 8;           // row * 256 u64
      const unsigned short* bp = p.W1Tb + (size_t)jcol*U_;
      f32x4 acc = (f32x4){0.f,0.f,0.f,0.f};
      #pragma unroll 8
      for (int k = 0; k < U_; k += 32){
        s16x8 a8 = frag_ald(hbRu + rbase + ((k + quad*8) >> 2));
        s16x8 b8 = *(const s16x8*)(bp + k + quad*8);
        acc = __builtin_amdgcn_mfma_f32_16x16x32_bf16(a8, b8, acc, 0, 0, 0);
      }
      float bj = p.b1[jcol];
      float* tqs = smem;   // 16*68
      #pragma unroll
      for (int r = 0; r < 4; ++r)
        tqs[l15*68 + w*16 + quad*4 + r] = fast_tanh(acc[r] + bj);
      __syncthreads();
      if (t < 64){
        int ub64 = (t*U_ + bi*16) >> 1;        // float-pair index
        #pragma unroll
        for (int cc = 0; cc < 16; cc += 2){
          U64F2 x;
          x.f[0] = tqs[(cc+0)*68 + t];
          x.f[1] = tqs[(cc+1)*68 + t];
          ast64(tqu + ub64 + (cc >> 1), x.q);
        }
      }
    } else if (bi < 320){
      int bz = bi - 64;    // 16 cols each over 256 blocks
      int rbase = (w*16 + l15) << 8;
      int jc0 = bz*16 + l15;
      const unsigned short* bp0 = p.WrTb + (size_t)jc0*U_;
      f32x4 acc0 = (f32x4){0.f,0.f,0.f,0.f};
      #pragma unroll 8
      for (int k = 0; k < U_; k += 32){
        s16x8 a8 = frag_ald(hbRu + rbase + ((k + quad*8) >> 2));
        acc0 = __builtin_amdgcn_mfma_f32_16x16x32_bf16(a8, *(const s16x8*)(bp0 + k + quad*8), acc0, 0, 0, 0);
      }
      float bl0 = p.bl[jc0];
      int brow = w*16 + quad*4;
      U64F2 x;
      int i0 = (jc0*64 + brow) >> 1;
      x.f[0] = acc0[0] + bl0; x.f[1] = acc0[1] + bl0; ast64(zhu + i0, x.q);
      x.f[0] = acc0[2] + bl0; x.f[1] = acc0[3] + bl0; ast64(zhu + i0 + 1, x.q);
    } else if (bi >= 960){
      if (step > 0) out_reduce(p, bi - 960, step - 1, smem, t, lane, w);
    }

    gridbar(p.cnt, p.rel, ++barno);   // tq, zh at L3

    // ---- Phase B1: ew[b][t] = exp(score - Mb), all 1024 blocks: 16 t-rows each ----
    {
      int b = bi >> 4, tg = bi & 15;
      float tqv[16], Vv[16];
      int tqb = (b*U_ + lane*16) >> 1;
      #pragma unroll
      for (int i = 0; i < 8; ++i){
        U64F2 x; x.q = ald64(tqu + tqb + i);
        tqv[2*i] = x.f[0]; tqv[2*i+1] = x.f[1];
      }
      const float* Vp = p.V + lane*16;
      #pragma unroll
      for (int i = 0; i < 16; i += 4) *(f32x4*)&Vv[i] = *(const f32x4*)(Vp + i);
      int trow = tg*16 + w*4;
      const unsigned short* kp = p.tk + (size_t)(b*T_ + trow)*U_ + lane*16;
      float sr[4];
      #pragma unroll
      for (int rr = 0; rr < 4; ++rr){
        s16x8 k0 = *(const s16x8*)(kp + (size_t)rr*U_);
        s16x8 k1 = *(const s16x8*)(kp + (size_t)rr*U_ + 8);
        float s = 0.f;
        #pragma unroll
        for (int e = 0; e < 8; ++e){
          float kf = bf2f((unsigned short)k0[e]);
          float num = tqv[e] + kf;
          float den = fmaf(tqv[e], kf, 1.0f);
          s += Vv[e] * num * fast_rcp(den);
        }
        #pragma unroll
        for (int e = 0; e < 8; ++e){
          float kf = bf2f((unsigned short)k1[e]);
          float num = tqv[8+e] + kf;
          float den = fmaf(tqv[8+e], kf, 1.0f);
          s += Vv[8+e] * num * fast_rcp(den);
        }
        sr[rr] = s;
      }
      #pragma unroll
      for (int mk = 32; mk >= 1; mk >>= 1){
        #pragma unroll
        for (int rr = 0; rr < 4; ++rr) sr[rr] += __shfl_xor(sr[rr], mk, 64);
      }
      if (lane == 0){
        int eb = (b*T_ + trow) >> 1;
        #pragma unroll
        for (int j = 0; j < 2; ++j){
          U64F2 x;
          x.f[0] = __expf(sr[2*j]   - Mb);
          x.f[1] = __expf(sr[2*j+1] - Mb);
          ast64(ewu + eb + j, x.q);
        }
      }
    }

    gridbar(p.cnt, p.rel, ++barno);   // ew at L3

    // ---- Phase B2: denom + weighted ctx chunk, b = bi>>4, 64 u's each ----
    {
      int b = bi >> 4, ug = bi & 15;
      float* ewL = smem;        // 256
      float* tmp = smem + 256;  // 16
      float* red = smem + 272;  // 16*16*4 = 1024
      if (t < 128){
        U64F2 x; x.q = ald64(ewu + b*128 + t);
        ewL[2*t] = x.f[0]; ewL[2*t+1] = x.f[1];
      }
      __syncthreads();
      float e = ewL[t];
      float sum = e;
      #pragma unroll
      for (int mk = 32; mk >= 1; mk >>= 1) sum += __shfl_xor(sum, mk, 64);
      if (lane == 0) tmp[w] = sum;
      __syncthreads();
      float rd = fast_rcp(tmp[0] + tmp[1] + tmp[2] + tmp[3]);

      int ui = t & 15, tgp = t >> 4;
      int u = ug*64 + ui*4;
      const unsigned short* xp = p.xv + (size_t)b*T_*U_ + u;
      f32x4 a = (f32x4){0.f,0.f,0.f,0.f};
      #pragma unroll 4
      for (int t8 = tgp; t8 < T_; t8 += 16){
        float wg = ewL[t8];
        u16x4 x4 = *(const u16x4*)(xp + (size_t)t8*U_);
        a[0] = fmaf(wg, bf2f(x4[0]), a[0]);
        a[1] = fmaf(wg, bf2f(x4[1]), a[1]);
        a[2] = fmaf(wg, bf2f(x4[2]), a[2]);
        a[3] = fmaf(wg, bf2f(x4[3]), a[3]);
      }
      *(f32x4*)&red[(tgp*16 + ui)*4] = a;
      __syncthreads();
      if (t < 16){
        f32x4 r = (f32x4){0.f,0.f,0.f,0.f};
        #pragma unroll
        for (int g = 0; g < 16; ++g){
          f32x4 rr = *(f32x4*)&red[(g*16 + t)*4];
          r[0]+=rr[0]; r[1]+=rr[1]; r[2]+=rr[2]; r[3]+=rr[3];
        }
        U64H4 cv;
        cv.h[0]=f2bf(r[0]*rd); cv.h[1]=f2bf(r[1]*rd); cv.h[2]=f2bf(r[2]*rd); cv.h[3]=f2bf(r[3]*rd);
        ast64(ctxu + b*256 + ug*16 + t, cv.q);
      }
    }

    gridbar(p.cnt, p.rel, ++barno);   // ctxb at L3

    // ---- Phase C: z = ctx@Wk + zh, LSTM update (blocks 0..255, 4 u's each) ----
    if (bi < 256){
      int ub = bi*4;
      int gate = l15 >> 2, uo = l15 & 3;
      int jcol = gate*U_ + ub + uo;
      int rbase = (w*16 + l15) << 8;
      const unsigned short* bp0 = p.WkTb + (size_t)jcol*U_;
      f32x4 acc = (f32x4){0.f,0.f,0.f,0.f};
      #pragma unroll 8
      for (int k = 0; k < U_; k += 32){
        s16x8 a8 = frag_ald(ctxu + rbase + ((k + quad*8) >> 2));
        acc = __builtin_amdgcn_mfma_f32_16x16x32_bf16(a8, *(const s16x8*)(bp0 + k + quad*8), acc, 0, 0, 0);
      }
      int brow = w*16 + quad*4;
      int zi0 = (jcol*64 + brow) >> 1;
      U64F2 z0, z1;
      z0.q = ald64(zhu + zi0); z1.q = ald64(zhu + zi0 + 1);
      acc[0] += z0.f[0]; acc[1] += z0.f[1]; acc[2] += z1.f[0]; acc[3] += z1.f[1];
      float* zs = smem;          // 16*68 = 1088
      float* hs = smem + 1088;   // 256
      float* op = smem + 1344;   // 256
      *(f32x4*)&zs[l15*68 + brow] = acc;
      __syncthreads();
      {
        int b = t & 63, ui = t >> 6;   // ui in 0..3
        int u = ub + ui;
        float zi = zs[(0*4 + ui)*68 + b];
        float zf = zs[(1*4 + ui)*68 + b];
        float zg = zs[(2*4 + ui)*68 + b];
        float zo = zs[(3*4 + ui)*68 + b];
        float ig = fast_sig(zi), fg = fast_sig(zf);
        float gg = fast_tanh(zg), og = fast_sig(zo);
        float cold = p.c[u*64 + b];    // block-private: same block+CU across steps
        float cn = fg*cold + ig*gg;
        float hn = og * fast_tanh(cn);
        p.c[u*64 + b] = cn;
        hs[ui*64 + b] = hn;
        op[ui*64 + b] = hn * p.Wo[u];
      }
      __syncthreads();
      if (t < 64){
        U64H4 h0;
        #pragma unroll
        for (int k = 0; k < 4; ++k) h0.h[k] = f2bf(hs[k*64 + t]);
        ast64(hbWu + t*256 + bi, h0.q);
        float po = op[t] + op[64 + t] + op[128 + t] + op[192 + t];
        astf(&p.out_part[t*256 + bi], po);
      }
    }
  }

  gridbar(p.cnt, p.rel, ++barno);   // final out_part at L3
  if (bi >= 960) out_reduce(p, bi - 960, T_ - 1, smem, t, lane, w);
}

extern "C" void kernel_launch(void* const* d_in, const int* in_sizes, int n_in,
                              void* d_out, int out_size, void* d_ws, size_t ws_size,
                              hipStream_t stream){
  const float* inputs = (const float*)d_in[0];
  const float* We1 = (const float*)d_in[1];
  const float* be1 = (const float*)d_in[2];
  const float* We2 = (const float*)d_in[3];
  const float* be2 = (const float*)d_in[4];
  const float* W1  = (const float*)d_in[5];
  const float* b1  = (const float*)d_in[6];
  const float* W2  = (const float*)d_in[7];
  const float* b2  = (const float*)d_in[8];
  const float* V   = (const float*)d_in[9];
  // d_in[10] = bV: softmax shift-invariant, dropped
  const float* Wk  = (const float*)d_in[11];
  const float* Wr  = (const float*)d_in[12];
  const float* bl  = (const float*)d_in[13];
  const float* Wo  = (const float*)d_in[14];
  const float* bo  = (const float*)d_in[15];
  float* out = (float*)d_out;

  char* ws = (char*)d_ws;
  size_t off = 0;
  auto alloc = [&](size_t bytes) -> void* {
    void* pp = ws + off;
    off = (off + bytes + 255) & ~(size_t)255;
    return pp;
  };
  // h1 (GEMM-1 output) is dead after GEMM-2; tk (GEMM-3 output) aliases it.
  unsigned short* We1Tb = (unsigned short*)alloc((size_t)1024*128*2);
  unsigned short* We2Tb = (unsigned short*)alloc((size_t)1024*1024*2);
  unsigned short* W2Tb  = (unsigned short*)alloc((size_t)1024*1024*2);
  unsigned short* W1Tb  = (unsigned short*)alloc((size_t)1024*1024*2);
  unsigned short* WkTb  = (unsigned short*)alloc((size_t)4096*1024*2);
  unsigned short* WrTb  = (unsigned short*)alloc((size_t)4096*1024*2);
  unsigned short* h1tk  = (unsigned short*)alloc((size_t)BT_*U_*2);  // h1, then tk
  unsigned short* xv    = (unsigned short*)alloc((size_t)BT_*U_*2);
  float*          c     = (float*)alloc((size_t)B_*U_*4);
  unsigned short* hb0   = (unsigned short*)alloc((size_t)B_*U_*2);
  unsigned short* hb1   = (unsigned short*)alloc((size_t)B_*U_*2);
  unsigned short* ctxb  = (unsigned short*)alloc((size_t)B_*U_*2);
  float*          tq    = (float*)alloc((size_t)B_*U_*4);
  float*          ew    = (float*)alloc((size_t)B_*T_*4);
  float*          zh    = (float*)alloc((size_t)4*U_*64*4);
  float*          out_part = (float*)alloc((size_t)64*256*4);
  unsigned*       cnt   = (unsigned*)alloc(64*16*4);
  unsigned*       rel   = (unsigned*)alloc(64*16*4);
  float*          vbound= (float*)alloc(256);
  if (ws_size < off) return;  // workspace too small: fail loudly (validation mismatch)

  init_kernel<<<256, 256, 0, stream>>>(c, hb0, hb1, cnt, rel, V, vbound);
  transpose_bf_kernel<<<(128/32)*(1024/32),  256, 0, stream>>>(We1, We1Tb, 128, 1024);
  transpose_bf_kernel<<<(1024/32)*(1024/32), 256, 0, stream>>>(We2, We2Tb, 1024, 1024);
  transpose_bf_kernel<<<(1024/32)*(1024/32), 256, 0, stream>>>(W2,  W2Tb,  1024, 1024);
  transpose_bf_kernel<<<(1024/32)*(1024/32), 256, 0, stream>>>(W1,  W1Tb,  1024, 1024);
  transpose_bf_kernel<<<(1024/32)*(4096/32), 256, 0, stream>>>(Wk,  WkTb,  1024, 4096);
  transpose_bf_kernel<<<(1024/32)*(4096/32), 256, 0, stream>>>(Wr,  WrTb,  1024, 4096);

  gemm_embed<1><<<4096, 256, 0, stream>>>((const void*)inputs, We1Tb, be1, h1tk, DIN_, 0);
  gemm_embed<0><<<4096, 256, 0, stream>>>((const void*)h1tk,   We2Tb, be2, xv,   U_,   0);
  gemm_embed<0><<<4096, 256, 0, stream>>>((const void*)xv,     W2Tb,  b2,  h1tk, U_,   1);

  SeqP sp;
  sp.W1Tb = W1Tb; sp.WkTb = WkTb; sp.WrTb = WrTb; sp.tk = h1tk; sp.xv = xv;
  sp.b1 = b1; sp.bl = bl; sp.V = V; sp.Wo = Wo; sp.bo = bo; sp.vbound = vbound;
  sp.tq = tq; sp.ew = ew; sp.c = c; sp.zh = zh;
  sp.out_part = out_part; sp.out = out;
  sp.ctxb = ctxb; sp.hb0 = hb0; sp.hb1 = hb1; sp.cnt = cnt; sp.rel = rel;
  seq_kernel<<<dim3(G_), dim3(256), 0, stream>>>(sp);
}